// Round 1
// baseline (133.305 us; speedup 1.0000x reference)
//
#include <hip/hip_runtime.h>
#include <math.h>

#define D_BINS 59
#define CO     64
#define CI     256
#define NB     4
#define NC     6
#define H_IMG  16
#define W_IMG  44
#define HW     704            // H_IMG * W_IMG
#define NPIX   (NB*NC*HW)     // 16896
#define XD     128
#define YD     128
#define ZD     7
#define NOUT   123            // D_BINS + CO

// ---------------------------------------------------------------------------
// Kernel 1: invert the 24 cam2ego matrices in double precision.
// c2e is exactly [R t; 0 1]; inverse of full 4x4 equals [inv(A), -inv(A)t; 0 1].
// Double-precision adjugate matches np.linalg.inv to ~1e-15, avoiding
// depth-bin boundary flips downstream.
// ---------------------------------------------------------------------------
__global__ void k_inv(const float* __restrict__ c2e, float* __restrict__ e2c) {
    int i = threadIdx.x;
    if (i >= NB * NC) return;
    const float* M = c2e + i * 16;
    double a = M[0], b = M[1], c = M[2], t0 = M[3];
    double d = M[4], e = M[5], f = M[6], t1 = M[7];
    double g = M[8], h = M[9], ii = M[10], t2 = M[11];
    double A00 = e*ii - f*h, A01 = c*h - b*ii, A02 = b*f - c*e;
    double A10 = f*g - d*ii, A11 = a*ii - c*g, A12 = c*d - a*f;
    double A20 = d*h - e*g,  A21 = b*g - a*h,  A22 = a*e - b*d;
    double det = a*A00 + b*A10 + c*A20;
    double inv = 1.0 / det;
    double r00 = A00*inv, r01 = A01*inv, r02 = A02*inv;
    double r10 = A10*inv, r11 = A11*inv, r12 = A12*inv;
    double r20 = A20*inv, r21 = A21*inv, r22 = A22*inv;
    double s0 = -(r00*t0 + r01*t1 + r02*t2);
    double s1 = -(r10*t0 + r11*t1 + r12*t2);
    double s2 = -(r20*t0 + r21*t1 + r22*t2);
    float* o = e2c + i * 12;
    o[0] = (float)r00; o[1] = (float)r01; o[2]  = (float)r02; o[3]  = (float)s0;
    o[4] = (float)r10; o[5] = (float)r11; o[6]  = (float)r12; o[7]  = (float)s1;
    o[8] = (float)r20; o[9] = (float)r21; o[10] = (float)r22; o[11] = (float)s2;
}

// ---------------------------------------------------------------------------
// Kernel 2: depth/feat head. GEMM (pixels x 123 = W(123x256) @ img + b),
// softmax over first 59 -> depth output, last 64 -> feat workspace.
// Tile: 32 pixels x 128 outputs, K-chunks of 32, 4x4 register tile/thread.
//   A_lds: [32 k][36 px-stride]  (pad 4: conflict-free b128 reads)
//   W_lds: [32 k][132 o-stride]  (transposed store -> b128 reads)
//   X_lds: [32 px][124 o]        (reuses staging space post-GEMM)
// ---------------------------------------------------------------------------
__global__ __launch_bounds__(256) void k_head(
    const float* __restrict__ img, const float* __restrict__ wd,
    const float* __restrict__ bd, float* __restrict__ depth_out,
    float* __restrict__ feat_ws) {
    __shared__ float smem[5376];
    float* A_lds = smem;          // 32*36 = 1152 floats
    float* W_lds = smem + 1152;   // 32*132 = 4224 floats

    const int tid = threadIdx.x;
    const int ti = tid & 7;       // pixel group (px = ti*4 + i)
    const int tj = tid >> 3;      // output group (o = tj*4 + j), 0..31
    const int p0 = blockIdx.x * 32;   // 704 % 32 == 0 -> tile never crosses (b,n)
    const int bn = p0 / HW;
    const int hw0 = p0 % HW;
    const float* imgb = img + (size_t)bn * CI * HW + hw0;

    float acc[4][4];
#pragma unroll
    for (int i = 0; i < 4; ++i)
#pragma unroll
        for (int j = 0; j < 4; ++j) acc[i][j] = 0.f;

    for (int kc = 0; kc < 8; ++kc) {
        // stage A chunk: 32 channels x 32 pixels (coalesced float4)
        {
            int r = tid >> 3, c4 = tid & 7;
            float4 v = *(const float4*)(imgb + (size_t)(kc * 32 + r) * HW + c4 * 4);
            float* dst = A_lds + r * 36 + c4 * 4;
            *(float4*)dst = v;
        }
        // stage W chunk transposed: rows o 0..127 x 32 k
#pragma unroll
        for (int it = 0; it < 4; ++it) {
            int idx = tid + it * 256;
            int o = idx >> 3, c4 = idx & 7;
            float4 v = make_float4(0.f, 0.f, 0.f, 0.f);
            if (o < NOUT) v = *(const float4*)(wd + (size_t)o * CI + kc * 32 + c4 * 4);
            W_lds[(c4 * 4 + 0) * 132 + o] = v.x;
            W_lds[(c4 * 4 + 1) * 132 + o] = v.y;
            W_lds[(c4 * 4 + 2) * 132 + o] = v.z;
            W_lds[(c4 * 4 + 3) * 132 + o] = v.w;
        }
        __syncthreads();
#pragma unroll
        for (int k = 0; k < 32; ++k) {
            float4 a = *(const float4*)(A_lds + k * 36 + ti * 4);
            float4 w = *(const float4*)(W_lds + k * 132 + tj * 4);
            float av[4] = {a.x, a.y, a.z, a.w};
            float wv[4] = {w.x, w.y, w.z, w.w};
#pragma unroll
            for (int i = 0; i < 4; ++i)
#pragma unroll
                for (int j = 0; j < 4; ++j)
                    acc[i][j] = fmaf(av[i], wv[j], acc[i][j]);
        }
        __syncthreads();
    }

    // epilogue: X_lds[px][124] = acc + bias  (reuses smem; all compute done)
    float* X = smem;
    float bias[4];
#pragma unroll
    for (int j = 0; j < 4; ++j) {
        int o = tj * 4 + j;
        bias[j] = (o < NOUT) ? bd[o] : 0.f;
    }
#pragma unroll
    for (int i = 0; i < 4; ++i) {
        int px = ti * 4 + i;
#pragma unroll
        for (int j = 0; j < 4; ++j) {
            int o = tj * 4 + j;
            if (o < NOUT) X[px * 124 + o] = acc[i][j] + bias[j];
        }
    }
    __syncthreads();

    // feat: X[px][59..122] -> feat_ws[(p0+px)*64 + c]  (contiguous per wave)
    {
        int px = tid >> 3, q = tid & 7;
        const float* src = X + px * 124 + D_BINS + q * 8;
        float* dst = feat_ws + (size_t)(p0 + px) * CO + q * 8;
#pragma unroll
        for (int m = 0; m < 8; ++m) dst[m] = src[m];
    }

    // softmax over o 0..58, one thread per pixel
    if (tid < 32) {
        int px = tid;
        float* row = X + px * 124;
        float m = row[0];
        for (int o = 1; o < D_BINS; ++o) m = fmaxf(m, row[o]);
        float s = 0.f;
        for (int o = 0; o < D_BINS; ++o) {
            float e = __expf(row[o] - m);
            row[o] = e;
            s += e;
        }
        float* dout = depth_out + (size_t)(p0 + px) * D_BINS;
        for (int o = 0; o < D_BINS; ++o) dout[o] = row[o] / s;
    }
}

// ---------------------------------------------------------------------------
// Kernel 3: project voxels, gather depth weight + feat, splat to BEV.
// Block = (64 x, 4 c-quarters); thread owns one (b,y,x) cell x 16 channels.
// Stores: per channel, 64 lanes write 64 consecutive x -> fully coalesced.
// ---------------------------------------------------------------------------
__global__ __launch_bounds__(256) void k_splat(
    const float* __restrict__ e2c, const float* __restrict__ Kmat,
    const float* __restrict__ depth_g, const float* __restrict__ feat_ws,
    float* __restrict__ bev) {
    const int tx = threadIdx.x;          // 0..63 -> x
    const int cq = threadIdx.y;          // 0..3  -> channel quarter
    const int x = blockIdx.x * 64 + tx;
    const int y = blockIdx.y;
    const int b = blockIdx.z;
    const float wx = (float)x * 0.8f + (-51.2f);
    const float wy = (float)y * 0.8f + (-51.2f);

    float acc[16];
#pragma unroll
    for (int m = 0; m < 16; ++m) acc[m] = 0.f;

    for (int n = 0; n < NC; ++n) {
        const int bn = b * NC + n;
        const float* E = e2c + bn * 12;
        const float* Km = Kmat + bn * 9;
        const float k00 = Km[0], k01 = Km[1], k02 = Km[2];
        const float k10 = Km[3], k11 = Km[4], k12 = Km[5];
        const float e02 = E[2], e12 = E[6], e22 = E[10];
        const float bx0 = E[0] * wx + E[1] * wy + E[3];
        const float bx1 = E[4] * wx + E[5] * wy + E[7];
        const float bx2 = E[8] * wx + E[9] * wy + E[11];
#pragma unroll
        for (int z = 0; z < ZD; ++z) {
            const float wz = -2.5f + (float)z;
            const float cx = bx0 + e02 * wz;
            const float cy = bx1 + e12 * wz;
            const float cz = bx2 + e22 * wz;
            const float zs = fmaxf(cz, 0.1f);
            const float rz = 1.0f / zs;         // IEEE divide
            const float xn = cx * rz;
            const float yn = cy * rz;
            const float fu = (k00 * xn + k01 * yn + k02) * 0.0625f;
            const float fv = (k10 * xn + k11 * yn + k12) * 0.0625f;
            const int bin = (int)(cz - 1.0f);   // trunc-toward-zero, matches astype(int32)
            const bool valid = (fu >= 0.f) & (fu < (float)W_IMG) &
                               (fv >= 0.f) & (fv < (float)H_IMG) &
                               (cz > 0.5f) & (bin >= 0) & (bin < D_BINS);
            if (valid) {
                int u = (int)fu; u = u < 0 ? 0 : (u > W_IMG - 1 ? W_IMG - 1 : u);
                int v = (int)fv; v = v < 0 ? 0 : (v > H_IMG - 1 ? H_IMG - 1 : v);
                int hw = v * W_IMG + u;
                float wgt = depth_g[((size_t)bn * HW + hw) * D_BINS + bin];
                const float4* fp =
                    (const float4*)(feat_ws + ((size_t)bn * HW + hw) * CO + cq * 16);
                float4 f0 = fp[0], f1 = fp[1], f2 = fp[2], f3 = fp[3];
                acc[0]  = fmaf(wgt, f0.x, acc[0]);
                acc[1]  = fmaf(wgt, f0.y, acc[1]);
                acc[2]  = fmaf(wgt, f0.z, acc[2]);
                acc[3]  = fmaf(wgt, f0.w, acc[3]);
                acc[4]  = fmaf(wgt, f1.x, acc[4]);
                acc[5]  = fmaf(wgt, f1.y, acc[5]);
                acc[6]  = fmaf(wgt, f1.z, acc[6]);
                acc[7]  = fmaf(wgt, f1.w, acc[7]);
                acc[8]  = fmaf(wgt, f2.x, acc[8]);
                acc[9]  = fmaf(wgt, f2.y, acc[9]);
                acc[10] = fmaf(wgt, f2.z, acc[10]);
                acc[11] = fmaf(wgt, f2.w, acc[11]);
                acc[12] = fmaf(wgt, f3.x, acc[12]);
                acc[13] = fmaf(wgt, f3.y, acc[13]);
                acc[14] = fmaf(wgt, f3.z, acc[14]);
                acc[15] = fmaf(wgt, f3.w, acc[15]);
            }
        }
    }
    // out[b][c][y][x], c = cq*16 + m
    float* ob = bev + (((size_t)b * CO + cq * 16) * YD + y) * XD + x;
#pragma unroll
    for (int m = 0; m < 16; ++m) ob[(size_t)m * YD * XD] = acc[m];
}

extern "C" void kernel_launch(void* const* d_in, const int* in_sizes, int n_in,
                              void* d_out, int out_size, void* d_ws, size_t ws_size,
                              hipStream_t stream) {
    const float* img  = (const float*)d_in[0];  // (B,N,256,16,44)
    const float* c2e  = (const float*)d_in[1];  // (B,N,4,4)
    const float* Kmat = (const float*)d_in[2];  // (B,N,3,3)
    const float* wd   = (const float*)d_in[3];  // (123,256)
    const float* bd   = (const float*)d_in[4];  // (123,)
    float* bev = (float*)d_out;                         // (B,64,128,128)
    float* depth_out = bev + (size_t)NB * CO * YD * XD; // (B,N,16,44,59)
    float* feat_ws = (float*)d_ws;                      // NPIX*64 floats
    float* e2c = feat_ws + (size_t)NPIX * CO;           // 24*12 floats

    k_inv<<<1, 64, 0, stream>>>(c2e, e2c);
    k_head<<<NPIX / 32, 256, 0, stream>>>(img, wd, bd, depth_out, feat_ws);
    k_splat<<<dim3(2, YD, NB), dim3(64, 4, 1), 0, stream>>>(e2c, Kmat, depth_out,
                                                            feat_ws, bev);
}

// Round 2
// 130.716 us; speedup vs baseline: 1.0198x; 1.0198x over previous
//
#include <hip/hip_runtime.h>
#include <math.h>

#define D_BINS 59
#define CO     64
#define CI     256
#define NB     4
#define NC     6
#define H_IMG  16
#define W_IMG  44
#define HW     704            // H_IMG * W_IMG
#define NPIX   (NB*NC*HW)     // 16896
#define XD     128
#define YD     128
#define ZD     7
#define NOUT   123            // D_BINS + CO

// ---------------------------------------------------------------------------
// Device helper: double-precision rigid-transform inverse (matches
// np.linalg.inv to ~1e-15; avoids depth-bin boundary flips downstream).
// ---------------------------------------------------------------------------
__device__ void inv_rigid(const float* __restrict__ M, float* __restrict__ o) {
    double a = M[0], b = M[1], c = M[2], t0 = M[3];
    double d = M[4], e = M[5], f = M[6], t1 = M[7];
    double g = M[8], h = M[9], ii = M[10], t2 = M[11];
    double A00 = e*ii - f*h, A01 = c*h - b*ii, A02 = b*f - c*e;
    double A10 = f*g - d*ii, A11 = a*ii - c*g, A12 = c*d - a*f;
    double A20 = d*h - e*g,  A21 = b*g - a*h,  A22 = a*e - b*d;
    double det = a*A00 + b*A10 + c*A20;
    double inv = 1.0 / det;
    double r00 = A00*inv, r01 = A01*inv, r02 = A02*inv;
    double r10 = A10*inv, r11 = A11*inv, r12 = A12*inv;
    double r20 = A20*inv, r21 = A21*inv, r22 = A22*inv;
    o[0] = (float)r00; o[1] = (float)r01; o[2]  = (float)r02;
    o[3] = (float)(-(r00*t0 + r01*t1 + r02*t2));
    o[4] = (float)r10; o[5] = (float)r11; o[6]  = (float)r12;
    o[7] = (float)(-(r10*t0 + r11*t1 + r12*t2));
    o[8] = (float)r20; o[9] = (float)r21; o[10] = (float)r22;
    o[11] = (float)(-(r20*t0 + r21*t1 + r22*t2));
}

// ---------------------------------------------------------------------------
// Kernel 1: prep. (a) transpose W (123x256) -> wt (256 x 128, zero-padded)
// so k_head can stream W rows through the scalar cache; (b) block 0 also
// computes the 24 cam2ego inverses (absorbs the old k_inv launch).
// ---------------------------------------------------------------------------
__global__ __launch_bounds__(256) void k_pre(
    const float* __restrict__ wd, const float* __restrict__ c2e,
    float* __restrict__ wt, float* __restrict__ e2c) {
    const int o = blockIdx.x;   // 0..127
    const int k = threadIdx.x;  // 0..255
    float v = (o < NOUT) ? wd[(size_t)o * CI + k] : 0.f;
    wt[(size_t)k * 128 + o] = v;
    if (blockIdx.x == 0 && k < NB * NC)
        inv_rigid(c2e + k * 16, e2c + k * 12);
}

// ---------------------------------------------------------------------------
// Kernel 2: depth/feat head.
// Block (64 px, 8 waves); wave w owns outputs o0=w*16..+15 (wave-uniform ->
// W rows come in as s_load through the scalar cache, used as the SGPR
// operand of v_fma). A tile staged in LDS, read as conflict-free b32
// (lane = px). LDS traffic per FMA drops 8x vs the 4x4-register-tile GEMM.
// Epilogue: logits -> X (cols 0..58), feat -> X (cols 64..127, 16B-aligned),
// softmax + coalesced stores.
// ---------------------------------------------------------------------------
__global__ __launch_bounds__(512) void k_head(
    const float* __restrict__ img, const float* __restrict__ wt,
    const float* __restrict__ bd, float* __restrict__ depth_out,
    float* __restrict__ feat_ws) {
    __shared__ float smem[8448 + 64];   // A: [0,4096) during GEMM; X: 64x132 after
    float* A_lds = smem;
    float* S = smem + 8448;

    const int px = threadIdx.x;                      // 0..63
    const int tid = threadIdx.y * 64 + threadIdx.x;  // 0..511
    const int o0 = __builtin_amdgcn_readfirstlane(threadIdx.y << 4);  // wave-uniform
    const int p0 = blockIdx.x * 64;     // 704 % 64 == 0 -> never crosses (b,n)
    const int bn = p0 / HW;
    const int hw0 = p0 % HW;
    const float* imgb = img + (size_t)bn * CI * HW + hw0;

    float acc[16];
#pragma unroll
    for (int j = 0; j < 16; ++j) acc[j] = 0.f;

    for (int kc = 0; kc < 4; ++kc) {
        // stage A chunk: 64 channels x 64 pixels (coalesced float4)
#pragma unroll
        for (int it = 0; it < 2; ++it) {
            int idx = tid + it * 512;
            int r = idx >> 4, c4 = idx & 15;
            float4 v = *(const float4*)(imgb + (size_t)(kc * 64 + r) * HW + c4 * 4);
            *(float4*)(A_lds + r * 64 + c4 * 4) = v;
        }
        __syncthreads();
        const float* wr = wt + (size_t)(kc * 64) * 128 + o0;
#pragma unroll 4
        for (int k = 0; k < 64; ++k) {
            float a = A_lds[k * 64 + px];
            const float* w = wr + k * 128;   // wave-uniform address -> s_load
#pragma unroll
            for (int j = 0; j < 16; ++j)
                acc[j] = fmaf(a, w[j], acc[j]);
        }
        __syncthreads();
    }

    // epilogue into X[64][132]: logits at col o (<59), feat at col o+5 (64..127)
    float* X = smem;
#pragma unroll
    for (int j = 0; j < 16; ++j) {
        int o = o0 + j;
        if (o < NOUT) {
            int col = (o < D_BINS) ? o : o + 5;
            X[px * 132 + col] = acc[j] + bd[o];
        }
    }
    __syncthreads();

    // feat: X[px][64..127] -> feat_ws[(p0+px)*64 ...], coalesced float4
#pragma unroll
    for (int it = 0; it < 2; ++it) {
        int g = tid + it * 512;            // 0..1023
        int p = g >> 4, m = g & 15;
        float4 v = *(const float4*)(X + p * 132 + 64 + m * 4);
        *(float4*)(feat_ws + (size_t)(p0 + p) * CO + m * 4) = v;
    }

    // softmax over cols 0..58, one thread per pixel; exp in place, 1/s to S
    if (tid < 64) {
        float* row = X + tid * 132;
        float m = row[0];
        for (int o = 1; o < D_BINS; ++o) m = fmaxf(m, row[o]);
        float s = 0.f;
        for (int o = 0; o < D_BINS; ++o) {
            float e = __expf(row[o] - m);
            row[o] = e;
            s += e;
        }
        S[tid] = 1.f / s;
    }
    __syncthreads();

    // depth: block's region is contiguous [p0*59, (p0+64)*59) -> coalesced
    for (int g = tid; g < 64 * D_BINS; g += 512) {
        int p = g / D_BINS;
        int o = g - p * D_BINS;
        depth_out[(size_t)p0 * D_BINS + g] = X[p * 132 + o] * S[p];
    }
}

// ---------------------------------------------------------------------------
// Kernel 3: project voxels, gather depth weight + feat, splat to BEV.
// Block = (64 x, 4 c-quarters); thread owns one (b,y,x) cell x 16 channels.
// Stores: per channel, 64 lanes write 64 consecutive x -> fully coalesced.
// ---------------------------------------------------------------------------
__global__ __launch_bounds__(256) void k_splat(
    const float* __restrict__ e2c, const float* __restrict__ Kmat,
    const float* __restrict__ depth_g, const float* __restrict__ feat_ws,
    float* __restrict__ bev) {
    const int tx = threadIdx.x;          // 0..63 -> x
    const int cq = threadIdx.y;          // 0..3  -> channel quarter
    const int x = blockIdx.x * 64 + tx;
    const int y = blockIdx.y;
    const int b = blockIdx.z;
    const float wx = (float)x * 0.8f + (-51.2f);
    const float wy = (float)y * 0.8f + (-51.2f);

    float acc[16];
#pragma unroll
    for (int m = 0; m < 16; ++m) acc[m] = 0.f;

    for (int n = 0; n < NC; ++n) {
        const int bn = b * NC + n;
        const float* E = e2c + bn * 12;
        const float* Km = Kmat + bn * 9;
        const float k00 = Km[0], k01 = Km[1], k02 = Km[2];
        const float k10 = Km[3], k11 = Km[4], k12 = Km[5];
        const float e02 = E[2], e12 = E[6], e22 = E[10];
        const float bx0 = E[0] * wx + E[1] * wy + E[3];
        const float bx1 = E[4] * wx + E[5] * wy + E[7];
        const float bx2 = E[8] * wx + E[9] * wy + E[11];
#pragma unroll
        for (int z = 0; z < ZD; ++z) {
            const float wz = -2.5f + (float)z;
            const float cx = bx0 + e02 * wz;
            const float cy = bx1 + e12 * wz;
            const float cz = bx2 + e22 * wz;
            const float zs = fmaxf(cz, 0.1f);
            const float rz = 1.0f / zs;         // IEEE divide
            const float xn = cx * rz;
            const float yn = cy * rz;
            const float fu = (k00 * xn + k01 * yn + k02) * 0.0625f;
            const float fv = (k10 * xn + k11 * yn + k12) * 0.0625f;
            const int bin = (int)(cz - 1.0f);   // trunc, matches astype(int32)
            const bool valid = (fu >= 0.f) & (fu < (float)W_IMG) &
                               (fv >= 0.f) & (fv < (float)H_IMG) &
                               (cz > 0.5f) & (bin >= 0) & (bin < D_BINS);
            if (valid) {
                int u = (int)fu;                // valid => already in [0, W)
                int v = (int)fv;
                int hw = v * W_IMG + u;
                float wgt = depth_g[((size_t)bn * HW + hw) * D_BINS + bin];
                const float4* fp =
                    (const float4*)(feat_ws + ((size_t)bn * HW + hw) * CO + cq * 16);
                float4 f0 = fp[0], f1 = fp[1], f2 = fp[2], f3 = fp[3];
                acc[0]  = fmaf(wgt, f0.x, acc[0]);
                acc[1]  = fmaf(wgt, f0.y, acc[1]);
                acc[2]  = fmaf(wgt, f0.z, acc[2]);
                acc[3]  = fmaf(wgt, f0.w, acc[3]);
                acc[4]  = fmaf(wgt, f1.x, acc[4]);
                acc[5]  = fmaf(wgt, f1.y, acc[5]);
                acc[6]  = fmaf(wgt, f1.z, acc[6]);
                acc[7]  = fmaf(wgt, f1.w, acc[7]);
                acc[8]  = fmaf(wgt, f2.x, acc[8]);
                acc[9]  = fmaf(wgt, f2.y, acc[9]);
                acc[10] = fmaf(wgt, f2.z, acc[10]);
                acc[11] = fmaf(wgt, f2.w, acc[11]);
                acc[12] = fmaf(wgt, f3.x, acc[12]);
                acc[13] = fmaf(wgt, f3.y, acc[13]);
                acc[14] = fmaf(wgt, f3.z, acc[14]);
                acc[15] = fmaf(wgt, f3.w, acc[15]);
            }
        }
    }
    // out[b][c][y][x], c = cq*16 + m
    float* ob = bev + (((size_t)b * CO + cq * 16) * YD + y) * XD + x;
#pragma unroll
    for (int m = 0; m < 16; ++m) ob[(size_t)m * YD * XD] = acc[m];
}

extern "C" void kernel_launch(void* const* d_in, const int* in_sizes, int n_in,
                              void* d_out, int out_size, void* d_ws, size_t ws_size,
                              hipStream_t stream) {
    const float* img  = (const float*)d_in[0];  // (B,N,256,16,44)
    const float* c2e  = (const float*)d_in[1];  // (B,N,4,4)
    const float* Kmat = (const float*)d_in[2];  // (B,N,3,3)
    const float* wd   = (const float*)d_in[3];  // (123,256)
    const float* bd   = (const float*)d_in[4];  // (123,)
    float* bev = (float*)d_out;                         // (B,64,128,128)
    float* depth_out = bev + (size_t)NB * CO * YD * XD; // (B,N,16,44,59)
    float* feat_ws = (float*)d_ws;                      // NPIX*64 floats
    float* wt  = feat_ws + (size_t)NPIX * CO;           // 256*128 floats
    float* e2c = wt + 256 * 128;                        // 24*12 floats

    k_pre<<<128, 256, 0, stream>>>(wd, c2e, wt, e2c);
    k_head<<<NPIX / 64, dim3(64, 8, 1), 0, stream>>>(img, wt, bd, depth_out, feat_ws);
    k_splat<<<dim3(2, YD, NB), dim3(64, 4, 1), 0, stream>>>(e2c, Kmat, depth_out,
                                                            feat_ws, bev);
}